// Round 12
// baseline (144.851 us; speedup 1.0000x reference)
//
#include <hip/hip_runtime.h>
#include <hip/hip_bf16.h>

#define EPS 1e-6f

typedef __attribute__((ext_vector_type(8))) __bf16 bf16x8;
typedef __attribute__((ext_vector_type(4))) float f32x4;

// ---------------------------------------------------------------------------
// Fully fused yat-similarity kernel — 256x256 tile, 1024 threads.
// 16 waves (4x4 grid, 64x64 per wave) => 4 waves/SIMD; acc 64 AGPR + 64 VGPR
// = exactly the 128-reg cap (tripwire: VGPR_Count 64, WRITE_SIZE 65536).
// vs r11 (58.8us): PHASE REORDER — ds_reads issued FIRST in each phase, then
// staging (vmcnt-wait + cvt + ds_writes) + next-tile issues, then MFMA.
// Rationale: LDS ops complete in-order per wave; with writes first, each
// wave's MFMA waited behind its own staging chain (vmcnt wait -> cvt -> 4
// ds_writes -> 8 ds_reads). Reads-first lets MFMA wait only lgkmcnt(writes
// outstanding) and overlaps the staging VALU with read latency.
// out = dots^2 / (xsq + psq - 2*dots + eps)
// ---------------------------------------------------------------------------
__global__ __launch_bounds__(1024, 4) void yat_fused(
    const float* __restrict__ X, const float* __restrict__ Pr,
    float* __restrict__ out, int M, int N, int K) {

    __shared__ __align__(128) char sm[131072];   // 2 slots x (A 32KB + B 32KB)
    __shared__ __align__(16) float sqx[256];
    __shared__ __align__(16) float sqp[256];
    const char* smc = (const char*)sm;

    const int t = threadIdx.x;
    const int lane = t & 63;
    const int wid = t >> 6;        // 0..15
    const int wr = wid >> 2;       // 0..3  (64-row band)
    const int wc = wid & 3;        // 0..3  (64-col band)

    // T1: bijective XCD swizzle (total % 8 == 0 guaranteed by launch guard)
    const int nbx = N >> 8;
    const int nby = M >> 8;
    const int total = nbx * nby;
    int bid = blockIdx.x;
    bid = (bid & 7) * (total >> 3) + (bid >> 3);
    const int by = bid / nbx;
    const int bx = bid - by * nbx;
    const int brow = by << 8;
    const int bcol = bx << 8;

    const int NKT = K >> 6;         // K-tiles (16)

    f32x4 acc[4][4];
#pragma unroll
    for (int i = 0; i < 4; ++i)
#pragma unroll
        for (int j = 0; j < 4; ++j) acc[i][j] = (f32x4){0.f, 0.f, 0.f, 0.f};

    const int arow = lane & 15;           // fragment row/col within 16
    const int kq16 = (lane >> 4) * 16;    // byte offset of k-slot within 32-k half

    // ---- staging geometry ----
    // Chunk s in {0,1}: thread owns row rl = s*128 + wid*8 + (lane>>3) of the
    // 256-row panel, logical col16 lcq = (lane&7)^(lane>>3) (pre-swizzled so
    // the LDS image lands at physical col16 = lane&7, i.e. byte lane*16).
    const int rsub = lane >> 3;
    const int lcq = (lane & 7) ^ rsub;
    const long baseA = (long)(brow + wid * 8 + rsub) * K + lcq * 8;
    const long baseB = (long)(bcol + wid * 8 + rsub) * K + lcq * 8;
    const long sH = (long)128 * K;  // uniform (SGPR)
    const int dlane = wid * 1024 + lane * 16;

    f32x4 c0[2], c1[2];             // ping-pong chunk buffers (8 regs each)
    float qA[2] = {0.f, 0.f};       // per-thread sum-of-squares
    float qB[2] = {0.f, 0.f};

    // issue chunk: 2 f32x4 = 8 k-elems of row-chunk s of one matrix, tile kt
#define ISSUE(buf, G, BASE, s, kt) do {                                        \
    const float* g0_ = (G) + BASE + (s) * sH + (long)(kt) * 64;                \
    buf[0] = *(const f32x4*)(g0_);                                             \
    buf[1] = *(const f32x4*)(g0_ + 4);                                         \
} while (0)

    // cvt + sumsq + ds_write chunk into slot (boff = 0 for A, 32768 for B)
#define WRITE(buf, Q, s, slot, boff) do {                                      \
    f32x4 u_ = buf[0], v_ = buf[1];                                            \
    Q[s] += u_[0]*u_[0] + u_[1]*u_[1] + u_[2]*u_[2] + u_[3]*u_[3]              \
          + v_[0]*v_[0] + v_[1]*v_[1] + v_[2]*v_[2] + v_[3]*v_[3];             \
    bf16x8 pk_;                                                                \
    _Pragma("unroll")                                                          \
    for (int i_ = 0; i_ < 4; ++i_) {                                           \
        pk_[i_]     = (__bf16)u_[i_];                                          \
        pk_[4 + i_] = (__bf16)v_[i_];                                          \
    }                                                                          \
    *(bf16x8*)((char*)sm + (slot) * 65536 + (boff) + (s) * 16384 + dlane) = pk_;\
} while (0)

    // read A/B fragments for one 32-k slice kk of the 64-k tile
#define READ_A(slot, kk) do {                                                  \
    _Pragma("unroll")                                                          \
    for (int mi_ = 0; mi_ < 4; ++mi_) {                                        \
        int r_ = wr * 64 + mi_ * 16 + arow;                                    \
        const char* p_ = smc + (slot) * 65536 + r_ * 128;                      \
        int s_ = (r_ & 7) << 4;                                                \
        af[mi_] = *(const bf16x8*)(p_ + (((kk) * 64 + kq16) ^ s_));            \
    }                                                                          \
} while (0)

#define READ_B(slot, kk) do {                                                  \
    _Pragma("unroll")                                                          \
    for (int ni_ = 0; ni_ < 4; ++ni_) {                                        \
        int r_ = wc * 64 + ni_ * 16 + arow;                                    \
        const char* p_ = smc + (slot) * 65536 + 32768 + r_ * 128;              \
        int s_ = (r_ & 7) << 4;                                                \
        bf[ni_] = *(const bf16x8*)(p_ + (((kk) * 64 + kq16) ^ s_));            \
    }                                                                          \
} while (0)

#define MFMA_S() do {                                                          \
    _Pragma("unroll")                                                          \
    for (int mi_ = 0; mi_ < 4; ++mi_)                                          \
        _Pragma("unroll")                                                      \
        for (int ni_ = 0; ni_ < 4; ++ni_)                                      \
            acc[mi_][ni_] = __builtin_amdgcn_mfma_f32_16x16x32_bf16(           \
                af[mi_], bf[ni_], acc[mi_][ni_], 0, 0, 0);                     \
} while (0)

#define PBAR() do {                                                            \
    __builtin_amdgcn_s_barrier();                                              \
    asm volatile("" ::: "memory");                                             \
} while (0)
#define LGKMDRAIN() asm volatile("s_waitcnt lgkmcnt(0)" ::: "memory")

    bf16x8 af[4];                 // A frags, one 32-k slice
    bf16x8 bf[4];                 // B frags, one 32-k slice

    // prologue: stage tile 0 via chunk ping-pong; leave c0/c1 = A(kt=1).
    ISSUE(c0, X, baseA, 0, 0);  ISSUE(c1, X, baseA, 1, 0);
    WRITE(c0, qA, 0, 0, 0);     WRITE(c1, qA, 1, 0, 0);
    ISSUE(c0, Pr, baseB, 0, 0); ISSUE(c1, Pr, baseB, 1, 0);
    WRITE(c0, qB, 0, 0, 32768); WRITE(c1, qB, 1, 0, 32768);
    if (NKT > 1) { ISSUE(c0, X, baseA, 0, 1); ISSUE(c1, X, baseA, 1, 1); }
    LGKMDRAIN();
    PBAR();

    for (int kt = 0; kt < NKT; ++kt) {
        const int slot = kt & 1;
        const int nslot = slot ^ 1;
        const bool more = (kt + 1) < NKT;
        const bool more2 = (kt + 2) < NKT;

        // ph1: reads FIRST (k-slice 0), then staging, then MFMA
        READ_A(slot, 0); READ_B(slot, 0);
        if (more) {
            WRITE(c0, qA, 0, nslot, 0);  ISSUE(c0, Pr, baseB, 0, kt + 1);
            WRITE(c1, qA, 1, nslot, 0);  ISSUE(c1, Pr, baseB, 1, kt + 1);
        }
        MFMA_S(); PBAR();
        // ph2: reads FIRST (k-slice 1), then staging, then MFMA, drain, bar
        READ_A(slot, 1); READ_B(slot, 1);
        if (more) {
            WRITE(c0, qB, 0, nslot, 32768);
            WRITE(c1, qB, 1, nslot, 32768);
        }
        if (more2) { ISSUE(c0, X, baseA, 0, kt + 2); ISSUE(c1, X, baseA, 1, kt + 2); }
        MFMA_S();
        LGKMDRAIN();
        PBAR();
    }

#undef ISSUE
#undef WRITE
#undef READ_A
#undef READ_B
#undef MFMA_S
#undef PBAR
#undef LGKMDRAIN

    // ---- reduce per-thread sum-of-squares into sqx/sqp ----
    // Row (s*128 + wid*8 + rsub) is covered by the 8 lanes sharing rsub:
    // 3-step shfl_xor over lane&7.
#pragma unroll
    for (int s = 0; s < 2; ++s) {
        float a = qA[s], b = qB[s];
#pragma unroll
        for (int m = 1; m <= 4; m <<= 1) {
            a += __shfl_xor(a, m);
            b += __shfl_xor(b, m);
        }
        if ((lane & 7) == 0) {
            int r = s * 128 + wid * 8 + rsub;
            sqx[r] = a;
            sqp[r] = b;
        }
    }

    // epilogue: score = d^2 / (xsq + psq - 2d + eps), staged through LDS
    // (128 rows x 256 cols f32 = 128KB = sm) for full-line f32x4 stores.
    // Two passes of 128 rows (wr>>1 half each). Swizzle: logical (row,col)
    // at physical col ^ (((row>>2)&1)<<4); reader loads physical
    // (c0l)^swz (logical cols [c0l,+3]) and stores to bcol + c0l.
    float* smf = (float*)sm;
#pragma unroll
    for (int pass = 0; pass < 2; ++pass) {
        __syncthreads();
        if ((wr >> 1) == pass) {
            const int wrl = wr & 1;
#pragma unroll
            for (int ni = 0; ni < 4; ++ni) {
                int lcc = wc * 64 + ni * 16 + arow;
                float ps = sqp[lcc];
#pragma unroll
                for (int mi = 0; mi < 4; ++mi) {
                    f32x4 c = acc[mi][ni];
                    int lr0 = wrl * 64 + mi * 16 + (lane >> 4) * 4;  // mult of 4
                    f32x4 xs4 = *(const f32x4*)(&sqx[pass * 128 + lr0]);
                    int lcs = lcc ^ (((lr0 >> 2) & 1) << 4);
#pragma unroll
                    for (int j = 0; j < 4; ++j) {
                        float dv = c[j];
                        float denom = xs4[j] + ps - 2.0f * dv + EPS;
                        smf[(lr0 + j) * 256 + lcs] = dv * dv / denom;
                    }
                }
            }
        }
        __syncthreads();
#pragma unroll
        for (int it = 0; it < 8; ++it) {
            int r = it * 16 + (t >> 6);
            int swz = ((r >> 2) & 1) << 4;
            int c0l = (t & 63) * 4;                         // logical col
            f32x4 v = *(const f32x4*)(smf + r * 256 + (c0l ^ swz));
            *(f32x4*)(out + (size_t)(brow + pass * 128 + r) * N + bcol + c0l) = v;
        }
    }
}

__global__ void yat_fallback(const float* __restrict__ x, const float* __restrict__ p,
                             float* __restrict__ out, int B, int P, int D) {
    __shared__ float xs[1024];
    int b = blockIdx.x;
    int pc = blockIdx.y * 256 + threadIdx.x;
    for (int i = threadIdx.x; i < D; i += 256) xs[i] = x[(size_t)b * D + i];
    __syncthreads();
    if (pc >= P) return;
    float dot = 0.f, psq = 0.f, xsq = 0.f;
    for (int k = 0; k < D; ++k) {
        float pv = p[(size_t)pc * D + k];
        float xv = xs[k];
        dot += xv * pv;
        psq += pv * pv;
        xsq += xv * xv;
    }
    float denom = xsq + psq - 2.f * dot + EPS;
    out[(size_t)b * P + pc] = dot * dot / denom;
}

extern "C" void kernel_launch(void* const* d_in, const int* in_sizes, int n_in,
                              void* d_out, int out_size, void* d_ws, size_t ws_size,
                              hipStream_t stream) {
    const float* x = (const float*)d_in[0];
    const float* p = (const float*)d_in[1];
    float* out = (float*)d_out;

    const int D = 1024;
    const int B = in_sizes[0] / D;
    const int P = in_sizes[1] / D;

    int nblocks = (B / 256) * (P / 256);
    if ((B % 256) || (P % 256) || (D % 64) || (nblocks % 8)) {
        yat_fallback<<<dim3(B, (P + 255) / 256), 256, 0, stream>>>(x, p, out, B, P, D);
        return;
    }

    yat_fused<<<dim3(nblocks), 1024, 0, stream>>>(x, p, out, B, P, D);
}

// Round 13
// 58.840 us; speedup vs baseline: 2.4618x; 2.4618x over previous
//
#include <hip/hip_runtime.h>
#include <hip/hip_bf16.h>

#define EPS 1e-6f

typedef __attribute__((ext_vector_type(8))) __bf16 bf16x8;
typedef __attribute__((ext_vector_type(4))) float f32x4;

// ---------------------------------------------------------------------------
// Fully fused yat-similarity kernel — 256x256 tile, 1024 threads. (= r11,
// the measured champion: 58.8us. r12's read-first reorder spilled: at the
// exact 128-reg/4-wave equilibrium, WRITE(old chunks) -> READ(frags) -> MFMA
// is the unique live-range order that fits; do not reorder.)
// 16 waves (4x4 grid, 64x64 per wave) => 4 waves/SIMD; acc 64 AGPR + 64 VGPR.
// f32 inputs reg-staged (2x 8-reg ping-pong chunks, issue->write = 1 phase),
// bf16 RTNE cvt + row sum-of-squares at write time.
// out = dots^2 / (xsq + psq - 2*dots + eps)
// ---------------------------------------------------------------------------
__global__ __launch_bounds__(1024, 4) void yat_fused(
    const float* __restrict__ X, const float* __restrict__ Pr,
    float* __restrict__ out, int M, int N, int K) {

    __shared__ __align__(128) char sm[131072];   // 2 slots x (A 32KB + B 32KB)
    __shared__ __align__(16) float sqx[256];
    __shared__ __align__(16) float sqp[256];
    const char* smc = (const char*)sm;

    const int t = threadIdx.x;
    const int lane = t & 63;
    const int wid = t >> 6;        // 0..15
    const int wr = wid >> 2;       // 0..3  (64-row band)
    const int wc = wid & 3;        // 0..3  (64-col band)

    // T1: bijective XCD swizzle (total % 8 == 0 guaranteed by launch guard)
    const int nbx = N >> 8;
    const int nby = M >> 8;
    const int total = nbx * nby;
    int bid = blockIdx.x;
    bid = (bid & 7) * (total >> 3) + (bid >> 3);
    const int by = bid / nbx;
    const int bx = bid - by * nbx;
    const int brow = by << 8;
    const int bcol = bx << 8;

    const int NKT = K >> 6;         // K-tiles (16)

    f32x4 acc[4][4];
#pragma unroll
    for (int i = 0; i < 4; ++i)
#pragma unroll
        for (int j = 0; j < 4; ++j) acc[i][j] = (f32x4){0.f, 0.f, 0.f, 0.f};

    const int arow = lane & 15;           // fragment row/col within 16
    const int kq16 = (lane >> 4) * 16;    // byte offset of k-slot within 32-k half

    // ---- staging geometry ----
    // Chunk s in {0,1}: thread owns row rl = s*128 + wid*8 + (lane>>3) of the
    // 256-row panel, logical col16 lcq = (lane&7)^(lane>>3) (pre-swizzled so
    // the LDS image lands at physical col16 = lane&7, i.e. byte lane*16).
    const int rsub = lane >> 3;
    const int lcq = (lane & 7) ^ rsub;
    const long baseA = (long)(brow + wid * 8 + rsub) * K + lcq * 8;
    const long baseB = (long)(bcol + wid * 8 + rsub) * K + lcq * 8;
    const long sH = (long)128 * K;  // uniform (SGPR)
    const int dlane = wid * 1024 + lane * 16;

    f32x4 c0[2], c1[2];             // ping-pong chunk buffers (8 regs each)
    float qA[2] = {0.f, 0.f};       // per-thread sum-of-squares
    float qB[2] = {0.f, 0.f};

    // issue chunk: 2 f32x4 = 8 k-elems of row-chunk s of one matrix, tile kt
#define ISSUE(buf, G, BASE, s, kt) do {                                        \
    const float* g0_ = (G) + BASE + (s) * sH + (long)(kt) * 64;                \
    buf[0] = *(const f32x4*)(g0_);                                             \
    buf[1] = *(const f32x4*)(g0_ + 4);                                         \
} while (0)

    // cvt + sumsq + ds_write chunk into slot (boff = 0 for A, 32768 for B)
#define WRITE(buf, Q, s, slot, boff) do {                                      \
    f32x4 u_ = buf[0], v_ = buf[1];                                            \
    Q[s] += u_[0]*u_[0] + u_[1]*u_[1] + u_[2]*u_[2] + u_[3]*u_[3]              \
          + v_[0]*v_[0] + v_[1]*v_[1] + v_[2]*v_[2] + v_[3]*v_[3];             \
    bf16x8 pk_;                                                                \
    _Pragma("unroll")                                                          \
    for (int i_ = 0; i_ < 4; ++i_) {                                           \
        pk_[i_]     = (__bf16)u_[i_];                                          \
        pk_[4 + i_] = (__bf16)v_[i_];                                          \
    }                                                                          \
    *(bf16x8*)((char*)sm + (slot) * 65536 + (boff) + (s) * 16384 + dlane) = pk_;\
} while (0)

    // read A/B fragments for one 32-k slice kk of the 64-k tile
#define READ_A(slot, kk) do {                                                  \
    _Pragma("unroll")                                                          \
    for (int mi_ = 0; mi_ < 4; ++mi_) {                                        \
        int r_ = wr * 64 + mi_ * 16 + arow;                                    \
        const char* p_ = smc + (slot) * 65536 + r_ * 128;                      \
        int s_ = (r_ & 7) << 4;                                                \
        af[mi_] = *(const bf16x8*)(p_ + (((kk) * 64 + kq16) ^ s_));            \
    }                                                                          \
} while (0)

#define READ_B(slot, kk) do {                                                  \
    _Pragma("unroll")                                                          \
    for (int ni_ = 0; ni_ < 4; ++ni_) {                                        \
        int r_ = wc * 64 + ni_ * 16 + arow;                                    \
        const char* p_ = smc + (slot) * 65536 + 32768 + r_ * 128;              \
        int s_ = (r_ & 7) << 4;                                                \
        bf[ni_] = *(const bf16x8*)(p_ + (((kk) * 64 + kq16) ^ s_));            \
    }                                                                          \
} while (0)

#define MFMA_S() do {                                                          \
    _Pragma("unroll")                                                          \
    for (int mi_ = 0; mi_ < 4; ++mi_)                                          \
        _Pragma("unroll")                                                      \
        for (int ni_ = 0; ni_ < 4; ++ni_)                                      \
            acc[mi_][ni_] = __builtin_amdgcn_mfma_f32_16x16x32_bf16(           \
                af[mi_], bf[ni_], acc[mi_][ni_], 0, 0, 0);                     \
} while (0)

#define PBAR() do {                                                            \
    __builtin_amdgcn_s_barrier();                                              \
    asm volatile("" ::: "memory");                                             \
} while (0)
#define LGKMDRAIN() asm volatile("s_waitcnt lgkmcnt(0)" ::: "memory")

    bf16x8 af[4];                 // A frags, one 32-k slice
    bf16x8 bf[4];                 // B frags, one 32-k slice

    // prologue: stage tile 0 via chunk ping-pong; leave c0/c1 = A(kt=1).
    ISSUE(c0, X, baseA, 0, 0);  ISSUE(c1, X, baseA, 1, 0);
    WRITE(c0, qA, 0, 0, 0);     WRITE(c1, qA, 1, 0, 0);
    ISSUE(c0, Pr, baseB, 0, 0); ISSUE(c1, Pr, baseB, 1, 0);
    WRITE(c0, qB, 0, 0, 32768); WRITE(c1, qB, 1, 0, 32768);
    if (NKT > 1) { ISSUE(c0, X, baseA, 0, 1); ISSUE(c1, X, baseA, 1, 1); }
    LGKMDRAIN();
    PBAR();

    for (int kt = 0; kt < NKT; ++kt) {
        const int slot = kt & 1;
        const int nslot = slot ^ 1;
        const bool more = (kt + 1) < NKT;
        const bool more2 = (kt + 2) < NKT;

        // ph1: write A(kt+1) -> nslot, issue B(kt+1); compute k-slice 0
        if (more) {
            WRITE(c0, qA, 0, nslot, 0);  ISSUE(c0, Pr, baseB, 0, kt + 1);
            WRITE(c1, qA, 1, nslot, 0);  ISSUE(c1, Pr, baseB, 1, kt + 1);
        }
        READ_A(slot, 0); READ_B(slot, 0);
        MFMA_S(); PBAR();
        // ph2: write B(kt+1) -> nslot, prime A(kt+2); compute k-slice 1
        if (more) {
            WRITE(c0, qB, 0, nslot, 32768);
            WRITE(c1, qB, 1, nslot, 32768);
        }
        if (more2) { ISSUE(c0, X, baseA, 0, kt + 2); ISSUE(c1, X, baseA, 1, kt + 2); }
        READ_A(slot, 1); READ_B(slot, 1);
        MFMA_S();
        LGKMDRAIN();
        PBAR();
    }

#undef ISSUE
#undef WRITE
#undef READ_A
#undef READ_B
#undef MFMA_S
#undef PBAR
#undef LGKMDRAIN

    // ---- reduce per-thread sum-of-squares into sqx/sqp ----
    // Row (s*128 + wid*8 + rsub) is covered by the 8 lanes sharing rsub:
    // 3-step shfl_xor over lane&7.
#pragma unroll
    for (int s = 0; s < 2; ++s) {
        float a = qA[s], b = qB[s];
#pragma unroll
        for (int m = 1; m <= 4; m <<= 1) {
            a += __shfl_xor(a, m);
            b += __shfl_xor(b, m);
        }
        if ((lane & 7) == 0) {
            int r = s * 128 + wid * 8 + rsub;
            sqx[r] = a;
            sqp[r] = b;
        }
    }

    // epilogue: score = d^2 / (xsq + psq - 2d + eps), staged through LDS
    // (128 rows x 256 cols f32 = 128KB = sm) for full-line f32x4 stores.
    // Two passes of 128 rows (wr>>1 half each). Swizzle: logical (row,col)
    // at physical col ^ (((row>>2)&1)<<4); reader loads physical
    // (c0l)^swz (logical cols [c0l,+3]) and stores to bcol + c0l.
    float* smf = (float*)sm;
#pragma unroll
    for (int pass = 0; pass < 2; ++pass) {
        __syncthreads();
        if ((wr >> 1) == pass) {
            const int wrl = wr & 1;
#pragma unroll
            for (int ni = 0; ni < 4; ++ni) {
                int lcc = wc * 64 + ni * 16 + arow;
                float ps = sqp[lcc];
#pragma unroll
                for (int mi = 0; mi < 4; ++mi) {
                    f32x4 c = acc[mi][ni];
                    int lr0 = wrl * 64 + mi * 16 + (lane >> 4) * 4;  // mult of 4
                    f32x4 xs4 = *(const f32x4*)(&sqx[pass * 128 + lr0]);
                    int lcs = lcc ^ (((lr0 >> 2) & 1) << 4);
#pragma unroll
                    for (int j = 0; j < 4; ++j) {
                        float dv = c[j];
                        float denom = xs4[j] + ps - 2.0f * dv + EPS;
                        smf[(lr0 + j) * 256 + lcs] = dv * dv / denom;
                    }
                }
            }
        }
        __syncthreads();
#pragma unroll
        for (int it = 0; it < 8; ++it) {
            int r = it * 16 + (t >> 6);
            int swz = ((r >> 2) & 1) << 4;
            int c0l = (t & 63) * 4;                         // logical col
            f32x4 v = *(const f32x4*)(smf + r * 256 + (c0l ^ swz));
            *(f32x4*)(out + (size_t)(brow + pass * 128 + r) * N + bcol + c0l) = v;
        }
    }
}

__global__ void yat_fallback(const float* __restrict__ x, const float* __restrict__ p,
                             float* __restrict__ out, int B, int P, int D) {
    __shared__ float xs[1024];
    int b = blockIdx.x;
    int pc = blockIdx.y * 256 + threadIdx.x;
    for (int i = threadIdx.x; i < D; i += 256) xs[i] = x[(size_t)b * D + i];
    __syncthreads();
    if (pc >= P) return;
    float dot = 0.f, psq = 0.f, xsq = 0.f;
    for (int k = 0; k < D; ++k) {
        float pv = p[(size_t)pc * D + k];
        float xv = xs[k];
        dot += xv * pv;
        psq += pv * pv;
        xsq += xv * xv;
    }
    float denom = xsq + psq - 2.f * dot + EPS;
    out[(size_t)b * P + pc] = dot * dot / denom;
}

extern "C" void kernel_launch(void* const* d_in, const int* in_sizes, int n_in,
                              void* d_out, int out_size, void* d_ws, size_t ws_size,
                              hipStream_t stream) {
    const float* x = (const float*)d_in[0];
    const float* p = (const float*)d_in[1];
    float* out = (float*)d_out;

    const int D = 1024;
    const int B = in_sizes[0] / D;
    const int P = in_sizes[1] / D;

    int nblocks = (B / 256) * (P / 256);
    if ((B % 256) || (P % 256) || (D % 64) || (nblocks % 8)) {
        yat_fallback<<<dim3(B, (P + 255) / 256), 256, 0, stream>>>(x, p, out, B, P, D);
        return;
    }

    yat_fused<<<dim3(nblocks), 1024, 0, stream>>>(x, p, out, B, P, D);
}